// Round 1
// baseline (172.826 us; speedup 1.0000x reference)
//
#include <hip/hip_runtime.h>

#define BB 16
#define TT 2048
#define VV 1024
// log(3.0)
#define LOG_THR 1.0986122886681098f

__global__ void ctc_stage1(const float* __restrict__ alpha,
                           const float* __restrict__ ctc,
                           const float* __restrict__ mask,
                           float* __restrict__ ws_sum,
                           int* __restrict__ ws_cnt) {
    const int b = blockIdx.x;
    const int tid = threadIdx.x;
    const float* arow = alpha + (size_t)b * TT;
    const float* mrow = mask + (size_t)b * TT;
    const float* crow = ctc + (size_t)b * TT * VV;   // blank column = element 0 of each row

    float s = 0.0f;
    int c = 0;
    for (int t = tid; t < TT; t += blockDim.x) {
        s += arow[t];
        float lp = crow[(size_t)t * VV];
        float mk = mrow[t];
        if ((1.0f - lp) > LOG_THR && mk != 0.0f) c++;
    }

    // intra-wave butterfly reduce (wave = 64)
    for (int off = 32; off > 0; off >>= 1) {
        s += __shfl_down(s, off, 64);
        c += __shfl_down(c, off, 64);
    }

    __shared__ float ssum[8];
    __shared__ int   scnt[8];
    const int wave = tid >> 6;
    if ((tid & 63) == 0) { ssum[wave] = s; scnt[wave] = c; }
    __syncthreads();
    if (tid == 0) {
        float ts = 0.0f; int tc = 0;
        const int nw = blockDim.x >> 6;
        for (int w = 0; w < nw; ++w) { ts += ssum[w]; tc += scnt[w]; }
        ws_sum[b] = ts;
        ws_cnt[b] = tc;
    }
}

__global__ void ctc_stage2(const float* __restrict__ ws_sum,
                           const int* __restrict__ ws_cnt,
                           const int* __restrict__ text_length,
                           float* __restrict__ out) {
    const int lane = threadIdx.x;  // single wave of 64

    float rs = 0.0f;
    int cnt = 0, tl = 0;
    if (lane < BB) {
        rs  = ws_sum[lane];
        cnt = ws_cnt[lane];
        tl  = text_length[lane];
    }

    // len_i = has_seg ? cnt : 1 ; inactive lanes contribute 0 to the maxes
    int len_i = (lane < BB) ? (cnt >= 1 ? cnt : 1) : 0;
    int tlv   = (lane < BB) ? tl : 0;

    int ml = len_i, mt = tlv;
    for (int off = 32; off > 0; off >>= 1) {
        ml = max(ml, __shfl_down(ml, off, 64));
        mt = max(mt, __shfl_down(mt, off, 64));
    }
    ml = __shfl(ml, 0, 64);
    mt = __shfl(mt, 0, 64);
    const int L = min(ml, mt);

    float per = 0.0f;
    if (lane < BB) {
        const int m = min(tl, L);
        if (cnt >= 1) {
            const int k = min(cnt, m);
            per = (float)k * fabsf(rs - 1.0f) + (float)max(0, m - cnt);
        } else {
            per = (float)max(0, m - 1);
        }
    }
    for (int off = 32; off > 0; off >>= 1) per += __shfl_down(per, off, 64);

    if (lane == 0) out[0] = per / (float)BB;
}

extern "C" void kernel_launch(void* const* d_in, const int* in_sizes, int n_in,
                              void* d_out, int out_size, void* d_ws, size_t ws_size,
                              hipStream_t stream) {
    const float* alpha       = (const float*)d_in[0];
    const float* ctc         = (const float*)d_in[1];
    const float* mask        = (const float*)d_in[2];
    const int*   text_length = (const int*)d_in[3];

    float* ws_sum = (float*)d_ws;                          // BB floats
    int*   ws_cnt = (int*)((char*)d_ws + 256);             // BB ints (aligned away from sums)
    float* out    = (float*)d_out;

    ctc_stage1<<<BB, 256, 0, stream>>>(alpha, ctc, mask, ws_sum, ws_cnt);
    ctc_stage2<<<1, 64, 0, stream>>>(ws_sum, ws_cnt, text_length, out);
}

// Round 2
// 169.018 us; speedup vs baseline: 1.0225x; 1.0225x over previous
//
#include <hip/hip_runtime.h>

#define BB 16
#define TT 2048
#define VV 1024
#define CH 16            // chunks per batch
#define CT (TT / CH)     // 128 threads per stage1 block
// log(3.0)
#define LOG_THR 1.0986122886681098f

// 256 blocks = (batch b = blockIdx.x>>4, chunk c = blockIdx.x&15), 128 thr each.
// One t-element per thread: all 32K blank-column gathers in flight chip-wide.
__global__ __launch_bounds__(CT) void ctc_stage1(
        const float* __restrict__ alpha,
        const float* __restrict__ ctc,
        const float* __restrict__ mask,
        float* __restrict__ ws_sum,
        int* __restrict__ ws_cnt) {
    const int b   = blockIdx.x >> 4;
    const int ch  = blockIdx.x & 15;
    const int tid = threadIdx.x;
    const int t   = ch * CT + tid;

    const size_t idx = (size_t)b * TT + t;
    float s  = alpha[idx];
    float mk = mask[idx];
    float lp = ctc[idx * (size_t)VV];   // blank column, one cache line per lane
    int   c  = ((1.0f - lp) > LOG_THR && mk != 0.0f) ? 1 : 0;

    // intra-wave butterfly (wave = 64)
    #pragma unroll
    for (int off = 32; off > 0; off >>= 1) {
        s += __shfl_xor(s, off, 64);
        c += __shfl_xor(c, off, 64);
    }

    __shared__ float ssum[CT / 64];
    __shared__ int   scnt[CT / 64];
    if ((tid & 63) == 0) { ssum[tid >> 6] = s; scnt[tid >> 6] = c; }
    __syncthreads();
    if (tid == 0) {
        float ts = 0.0f; int tc = 0;
        #pragma unroll
        for (int w = 0; w < CT / 64; ++w) { ts += ssum[w]; tc += scnt[w]; }
        ws_sum[b * CH + ch] = ts;
        ws_cnt[b * CH + ch] = tc;
    }
}

// One block, 256 threads: thread i -> (b = i>>4, chunk = i&15).
// Reduce the 16 chunks within each 16-lane shfl group, then lanes 0..15 of
// wave 0 run the closed-form per-sample loss and final sum.
__global__ __launch_bounds__(256) void ctc_stage2(
        const float* __restrict__ ws_sum,
        const int* __restrict__ ws_cnt,
        const int* __restrict__ text_length,
        float* __restrict__ out) {
    const int tid = threadIdx.x;   // 0..255

    float s = ws_sum[tid];         // coalesced: tid = b*16 + chunk
    int   c = ws_cnt[tid];
    #pragma unroll
    for (int off = 8; off > 0; off >>= 1) {  // reduce across the 16 chunks
        s += __shfl_xor(s, off, 64);
        c += __shfl_xor(c, off, 64);
    }

    __shared__ float rs_sh[BB];
    __shared__ int   cnt_sh[BB];
    if ((tid & 15) == 0) { rs_sh[tid >> 4] = s; cnt_sh[tid >> 4] = c; }
    __syncthreads();

    if (tid < BB) {   // lanes 0..15 of wave 0; shuffles stay within these lanes
        const float rs  = rs_sh[tid];
        const int   cnt = cnt_sh[tid];
        const int   tl  = text_length[tid];

        int len_i = (cnt >= 1) ? cnt : 1;
        int ml = len_i, mt = tl;
        #pragma unroll
        for (int off = 8; off > 0; off >>= 1) {
            ml = max(ml, __shfl_xor(ml, off, 64));
            mt = max(mt, __shfl_xor(mt, off, 64));
        }
        const int L = min(ml, mt);
        const int m = min(tl, L);

        float per;
        if (cnt >= 1) {
            const int k = min(cnt, m);
            per = (float)k * fabsf(rs - 1.0f) + (float)max(0, m - cnt);
        } else {
            per = (float)max(0, m - 1);
        }
        #pragma unroll
        for (int off = 8; off > 0; off >>= 1) per += __shfl_xor(per, off, 64);

        if (tid == 0) out[0] = per / (float)BB;
    }
}

extern "C" void kernel_launch(void* const* d_in, const int* in_sizes, int n_in,
                              void* d_out, int out_size, void* d_ws, size_t ws_size,
                              hipStream_t stream) {
    const float* alpha       = (const float*)d_in[0];
    const float* ctc         = (const float*)d_in[1];
    const float* mask        = (const float*)d_in[2];
    const int*   text_length = (const int*)d_in[3];

    float* ws_sum = (float*)d_ws;                       // 256 floats
    int*   ws_cnt = (int*)((char*)d_ws + 1024);         // 256 ints
    float* out    = (float*)d_out;

    ctc_stage1<<<BB * CH, CT, 0, stream>>>(alpha, ctc, mask, ws_sum, ws_cnt);
    ctc_stage2<<<1, 256, 0, stream>>>(ws_sum, ws_cnt, text_length, out);
}